// Round 10
// baseline (203.905 us; speedup 1.0000x reference)
//
#include <hip/hip_runtime.h>
#include <hip/hip_bf16.h>

#define B_N 8192
#define C_DIM 512
#define NT2 32           // 256-wide tiles per dimension
#define NTRI2 528        // NT2*(NT2+1)/2 upper-triangle tiles

typedef __attribute__((ext_vector_type(4))) float f32x4;
typedef __attribute__((ext_vector_type(8))) __bf16 bf16x8;
typedef __attribute__((address_space(3))) unsigned int lds_u32;
typedef const __attribute__((address_space(1))) unsigned int glb_u32;

__device__ __forceinline__ void gl_lds16(const unsigned short* g, unsigned short* l) {
    __builtin_amdgcn_global_load_lds((glb_u32*)g, (lds_u32*)l, 16, 0, 0);
}

__device__ __forceinline__ unsigned short f2bf(float f) {
    unsigned int u = __float_as_uint(f);
    u += 0x7FFFu + ((u >> 16) & 1u);          // RNE
    return (unsigned short)(u >> 16);
}
__device__ __forceinline__ float bf2f(unsigned int s) {
    return __uint_as_float(s << 16);
}
// order-preserving key: float order -> unsigned ascending. key 0 / 0xFFFF impossible for finite sims.
__device__ __forceinline__ unsigned negkey(unsigned ub) {
    return (ub & 0x8000u) ? ((~ub) & 0xFFFFu) : (ub | 0x8000u);
}
__device__ __forceinline__ unsigned unkey(unsigned k) {
    return (k & 0x8000u) ? (k ^ 0x8000u) : ((~k) & 0xFFFFu);
}

// ---- one-block prep: layout detect, class bytes, class member lists (counting sort) ----
__global__ void prep_all(const unsigned int* __restrict__ t, unsigned char* __restrict__ tgb,
                         unsigned short* __restrict__ clist, int* __restrict__ off) {
    __shared__ int bad, cnt[128], base[128];
    const int tid = threadIdx.x;
    if (tid == 0) bad = 0;
    if (tid < 128) cnt[tid] = 0;
    __syncthreads();
    int local = 0;
    for (int k = tid; k < 4096; k += 256)        // first 32KB only: safe for both layouts
        if (t[2 * k + 1] != 0u) local = 1;
    if (local) atomicOr(&bad, 1);
    __syncthreads();
    const int is64 = (bad == 0);
    for (int i = 0; i < 32; ++i) {
        int j = i * 256 + tid;
        unsigned c = (is64 ? t[2 * j] : t[j]) & 127u;   // classes < 100
        tgb[j] = (unsigned char)c;
        atomicAdd(&cnt[c], 1);
    }
    __syncthreads();
    if (tid == 0) {
        int s = 0;
        for (int c = 0; c < 128; ++c) { base[c] = s; off[c] = s; s += cnt[c]; }
        off[128] = s;
    }
    __syncthreads();
    for (int i = 0; i < 32; ++i) {
        int j = i * 256 + tid;
        unsigned c = (is64 ? t[2 * j] : t[j]) & 127u;
        int idx = atomicAdd(&base[c], 1);
        clist[idx] = (unsigned short)j;
    }
}

// ---- per-class membership words: cm2[c*256+t] bit (q*8+e) = (tgb[q*2048+t*8+e]==c) ----
__global__ void class_masks(const unsigned char* __restrict__ tgb,
                            unsigned int* __restrict__ cm2) {
    const int c = blockIdx.x, t = threadIdx.x;
    unsigned w = 0;
#pragma unroll
    for (int q = 0; q < 4; ++q) {
        const unsigned char* base = tgb + q * 2048 + t * 8;
        unsigned b = 0;
#pragma unroll
        for (int e = 0; e < 8; ++e)
            b |= ((unsigned)(base[e] == c)) << e;
        w |= b << (8 * q);
    }
    cm2[c * 256 + t] = w;
}

// ---- L2 normalize rows, emit bf16 ----
__global__ __launch_bounds__(256) void normalize_k(const float* __restrict__ x,
                                                   unsigned short* __restrict__ nf) {
    const int wid = threadIdx.x >> 6, lane = threadIdx.x & 63;
    const size_t row = (size_t)blockIdx.x * 4 + wid;
    const float4* xr = (const float4*)(x + row * C_DIM) + lane * 2;
    float4 a = xr[0], b = xr[1];
    float ss = a.x * a.x + a.y * a.y + a.z * a.z + a.w * a.w +
               b.x * b.x + b.y * b.y + b.z * b.z + b.w * b.w;
#pragma unroll
    for (int m = 1; m < 64; m <<= 1) ss += __shfl_xor(ss, m);
    float sc = 1.0f / fmaxf(sqrtf(ss), 1e-12f);
    union { unsigned short s[8]; int4 v; } o;
    o.s[0] = f2bf(a.x * sc); o.s[1] = f2bf(a.y * sc);
    o.s[2] = f2bf(a.z * sc); o.s[3] = f2bf(a.w * sc);
    o.s[4] = f2bf(b.x * sc); o.s[5] = f2bf(b.y * sc);
    o.s[6] = f2bf(b.z * sc); o.s[7] = f2bf(b.w * sc);
    *(int4*)(nf + row * C_DIM + lane * 8) = o.v;
}

// ---- 256x256-tile symmetric GEMM: sim keys = negkey(bf16(nf @ nf^T)) ----
// 8 waves (2x4), wave tile 128x64, BK=64, double-buffered LDS (128 KB),
// T3-minimum 2-phase: issue next STAGE before current ds_read+MFMA.
__global__ __launch_bounds__(512, 2) void gemm_sim256(const unsigned short* __restrict__ nf,
                                                      unsigned short* __restrict__ simk) {
    __shared__ unsigned short smem[2][32768];       // [buf][A 16K shorts | B 16K shorts]
    // bijective XCD chunk swizzle (528 % 8 == 0)
    const int id = ((int)blockIdx.x % 8) * (NTRI2 / 8) + (int)blockIdx.x / 8;
    const int idp = (NTRI2 - 1) - id;
    int u = (int)((sqrtf(8.0f * (float)idp + 1.0f) - 1.0f) * 0.5f);
    while (u * (u + 1) / 2 > idp) --u;
    while ((u + 1) * (u + 2) / 2 <= idp) ++u;
    const int v = idp - u * (u + 1) / 2;
    const int tI = (NT2 - 1) - u;
    const int tJ = (NT2 - 1) - v;

    const int tid = threadIdx.x;
    const int wid = tid >> 6, lane = tid & 63;
    const int wm = wid >> 2, wn = wid & 3;          // 2 x 4 wave grid
    const int gr = tI * 256;
    const int gc = tJ * 256;
    f32x4 zero = {0.f, 0.f, 0.f, 0.f};
    f32x4 acc[8][4];
#pragma unroll
    for (int m = 0; m < 8; ++m)
#pragma unroll
        for (int n = 0; n < 4; ++n) acc[m][n] = zero;

    const int lr = lane >> 3, lcb = lane & 7;

    // stage K-tile k0 into buffer b: 32 A-chunks + 32 B-chunks of (8 rows x 64 cols)
#define STAGE(b, k0)                                                              \
    {                                                                             \
        _Pragma("unroll")                                                         \
        for (int i = 0; i < 4; ++i) {                                             \
            const int chunk = wid * 4 + i;                                        \
            const int r = chunk * 8 + lr;                                         \
            const int sc = (lcb ^ (r & 7)) << 3;                                  \
            gl_lds16(nf + (size_t)(gr + r) * C_DIM + (k0) + sc,                   \
                     &smem[b][chunk * 512]);                                      \
            gl_lds16(nf + (size_t)(gc + r) * C_DIM + (k0) + sc,                   \
                     &smem[b][16384 + chunk * 512]);                              \
        }                                                                         \
    }

    STAGE(0, 0)
    __syncthreads();
    int cur = 0;
    for (int t = 0; t < C_DIM / 64; ++t) {
        if (t + 1 < C_DIM / 64) STAGE(cur ^ 1, (t + 1) * 64)
        const unsigned short* As = &smem[cur][0];
        const unsigned short* Bs = &smem[cur][16384];
#pragma unroll
        for (int kk = 0; kk < 2; ++kk) {
            const int krow = kk * 32 + (lane >> 4) * 8;
            bf16x8 a[8], b[4];
#pragma unroll
            for (int m = 0; m < 8; ++m) {
                const int R = wm * 128 + m * 16 + (lane & 15);
                a[m] = *(const bf16x8*)&As[R * 64 + (krow ^ ((R & 7) << 3))];
            }
#pragma unroll
            for (int n = 0; n < 4; ++n) {
                const int R = wn * 64 + n * 16 + (lane & 15);
                b[n] = *(const bf16x8*)&Bs[R * 64 + (krow ^ ((R & 7) << 3))];
            }
#pragma unroll
            for (int m = 0; m < 8; ++m)
#pragma unroll
                for (int n = 0; n < 4; ++n)
                    acc[m][n] = __builtin_amdgcn_mfma_f32_16x16x32_bf16(a[m], b[n], acc[m][n], 0, 0, 0);
        }
        __syncthreads();                            // drains vmcnt: next buffer ready
        cur ^= 1;
    }
#undef STAGE

    // direct write; C/D layout: col=lane&15, row=(lane>>4)*4+j
    const int lro = wm * 128 + ((lane >> 4) << 2);
    const int lco = wn * 64 + (lane & 15);
#pragma unroll
    for (int m = 0; m < 8; ++m)
#pragma unroll
        for (int n = 0; n < 4; ++n)
#pragma unroll
            for (int j = 0; j < 4; ++j)
                simk[(size_t)(gr + lro + m * 16 + j) * B_N + gc + lco + n * 16] =
                    (unsigned short)negkey(f2bf(acc[m][n][j]));

    if (tJ > tI) {
        // transposed write via four 64-col LDS bounces: Cs[64][264] = 33.8 KB in buf0
        unsigned short* Cs = &smem[0][0];
#pragma unroll
        for (int q = 0; q < 4; ++q) {
            if (wn == q) {
#pragma unroll
                for (int m = 0; m < 8; ++m)
#pragma unroll
                    for (int n = 0; n < 4; ++n) {
                        const int c = n * 16 + (lane & 15);          // 0..63
                        const int r0 = wm * 128 + m * 16 + ((lane >> 4) << 2);
                        ushort4 pk;
                        pk.x = (unsigned short)negkey(f2bf(acc[m][n][0]));
                        pk.y = (unsigned short)negkey(f2bf(acc[m][n][1]));
                        pk.z = (unsigned short)negkey(f2bf(acc[m][n][2]));
                        pk.w = (unsigned short)negkey(f2bf(acc[m][n][3]));
                        *(ushort4*)&Cs[c * 264 + r0] = pk;
                    }
            }
            __syncthreads();
            {
                const int c = tid >> 3;                              // 0..63
#pragma unroll
                for (int j2 = 0; j2 < 4; ++j2) {
                    const int rb = ((tid & 7) * 4 + j2) * 8;         // 0..248 step 8
                    int4 w = *(const int4*)&Cs[c * 264 + rb];
                    *(int4*)&simk[(size_t)(gc + q * 64 + c) * B_N + gr + rb] = w;
                }
            }
            __syncthreads();
        }
    }
}

// ---- fallback 128-tile GEMM for chunked path ----
__global__ __launch_bounds__(256) void gemm_sim(const unsigned short* __restrict__ nf,
                                                unsigned short* __restrict__ simk,
                                                int rowBase) {
    __shared__ unsigned short smem[128 * 128];
    unsigned short* As = smem;
    unsigned short* Bs = smem + 8192;
    const int tI = blockIdx.y, tJ = blockIdx.x;
    const int tid = threadIdx.x;
    const int wid = tid >> 6, lane = tid & 63;
    const int wm = wid >> 1, wn = wid & 1;
    const int gr = rowBase + tI * 128;
    const int gc = tJ * 128;
    f32x4 zero = {0.f, 0.f, 0.f, 0.f};
    f32x4 acc[4][4];
#pragma unroll
    for (int m = 0; m < 4; ++m)
#pragma unroll
        for (int n = 0; n < 4; ++n) acc[m][n] = zero;
    const int lr = lane >> 3, lcb = lane & 7;
    for (int k0 = 0; k0 < C_DIM; k0 += 64) {
#pragma unroll
        for (int i = 0; i < 4; ++i) {
            const int chunk = wid * 4 + i;
            const int r = chunk * 8 + lr;
            const int sc = (lcb ^ (r & 7)) << 3;
            gl_lds16(nf + (size_t)(gr + r) * C_DIM + k0 + sc, As + chunk * 512);
            gl_lds16(nf + (size_t)(gc + r) * C_DIM + k0 + sc, Bs + chunk * 512);
        }
        __syncthreads();
#pragma unroll
        for (int kk = 0; kk < 2; ++kk) {
            const int krow = kk * 32 + (lane >> 4) * 8;
            bf16x8 a[4], b[4];
#pragma unroll
            for (int m = 0; m < 4; ++m) {
                const int R = wm * 64 + m * 16 + (lane & 15);
                a[m] = *(const bf16x8*)&As[R * 64 + (krow ^ ((R & 7) << 3))];
            }
#pragma unroll
            for (int n = 0; n < 4; ++n) {
                const int R = wn * 64 + n * 16 + (lane & 15);
                b[n] = *(const bf16x8*)&Bs[R * 64 + (krow ^ ((R & 7) << 3))];
            }
#pragma unroll
            for (int m = 0; m < 4; ++m)
#pragma unroll
                for (int n = 0; n < 4; ++n)
                    acc[m][n] = __builtin_amdgcn_mfma_f32_16x16x32_bf16(a[m], b[n], acc[m][n], 0, 0, 0);
        }
        __syncthreads();
    }
    const int lro = wm * 64 + ((lane >> 4) << 2);
    const int lco = wn * 64 + (lane & 15);
#pragma unroll
    for (int m = 0; m < 4; ++m)
#pragma unroll
        for (int n = 0; n < 4; ++n)
#pragma unroll
            for (int j = 0; j < 4; ++j)
                simk[(size_t)(gr - rowBase + lro + m * 16 + j) * B_N + gc + lco + n * 16] =
                    (unsigned short)negkey(f2bf(acc[m][n][j]));
}

// ---- block-per-row selection + loss: premasked keys, 1024-bin hist, 2 scans ----
__global__ __launch_bounds__(256) void select_loss(const unsigned short* __restrict__ simk,
                                                   const unsigned char* __restrict__ tgb,
                                                   const unsigned int* __restrict__ cm2,
                                                   const unsigned short* __restrict__ clist,
                                                   const int* __restrict__ off,
                                                   float* __restrict__ out, int rowBase) {
    __shared__ int hG[2080];          // 2 groups x 1040 (1024 bins + pad bin>>6)
    __shared__ int lowh[64];
    __shared__ int nlist[64];
    __shared__ int blist[272];
    __shared__ float s_partial[4];
    __shared__ int s_T, s_krem, s_kb, s_thr, s_krem2, nln, bln;

    const int tid = threadIdx.x;
    const int wid = tid >> 6, lane = tid & 63;
    const int row = rowBase + blockIdx.x;
    const unsigned short* srow = simk + (size_t)blockIdx.x * B_N;
    const int ti = tgb[row];

    int4 A[4];
    const unsigned m = cm2[ti * 256 + tid];
#pragma unroll
    for (int q = 0; q < 4; ++q) {
        A[q] = *(const int4*)(srow + q * 2048 + tid * 8);
#pragma unroll
        for (int d = 0; d < 4; ++d) {
            unsigned two = (m >> (q * 8 + d * 2)) & 3u;
            unsigned kill = ((two & 1u) * 0xFFFFu) | (((two >> 1) & 1u) * 0xFFFF0000u);
            int v = (d == 0 ? A[q].x : d == 1 ? A[q].y : d == 2 ? A[q].z : A[q].w);
            v = (int)((unsigned)v & ~kill);
            if (d == 0) A[q].x = v; else if (d == 1) A[q].y = v;
            else if (d == 2) A[q].z = v; else A[q].w = v;
        }
    }

    for (int i = tid; i < 2080; i += 256) hG[i] = 0;
    if (tid < 64) lowh[tid] = 0;
    if (tid == 0) { nln = 0; bln = 0; }
    __syncthreads();                                             // B1

#define ELEM_LOOP(BODY)                                                          \
    _Pragma("unroll")                                                            \
    for (int q = 0; q < 4; ++q) {                                                \
        _Pragma("unroll")                                                        \
        for (int d = 0; d < 4; ++d) {                                            \
            unsigned w32 = (unsigned)(d == 0 ? A[q].x : d == 1 ? A[q].y          \
                                    : d == 2 ? A[q].z : A[q].w);                 \
            _Pragma("unroll")                                                    \
            for (int h2 = 0; h2 < 2; ++h2) {                                     \
                unsigned key = h2 ? (w32 >> 16) : (w32 & 0xFFFFu);               \
                BODY                                                             \
            }                                                                    \
        }                                                                        \
    }

    // scan 1: unconditional 1024-bin hist (half-wave groups, padded addressing)
    int* hGg = hG + ((tid >> 5) & 1) * 1040;
    ELEM_LOOP(
        unsigned bin = key >> 6;
        atomicAdd(&hGg[bin + (bin >> 6)], 1);
    )
    __syncthreads();                                             // B2

    // wave0: find threshold bin T (top-64) over 1024 bins
    if (wid == 0) {
        int hv[16]; int tl = 0;
#pragma unroll
        for (int i = 0; i < 16; ++i) {
            int b = lane * 16 + i;
            int a = hG[b + (b >> 6)] + hG[1040 + b + (b >> 6)];
            hv[i] = a; tl += a;
        }
        int s = tl;
#pragma unroll
        for (int o = 1; o < 64; o <<= 1) {
            int v = __shfl_down(s, o);
            if (lane + o < 64) s += v;
        }
        const int E = s - tl;                    // sum over lanes above
        int cnt = E, Ti = -1, kremi = 0, kbi = 0;
#pragma unroll
        for (int i = 15; i >= 0; --i) {
            bool cross = (cnt < 64) && (cnt + hv[i] >= 64);
            if (cross) { Ti = i; kremi = 64 - cnt; kbi = hv[i]; }
            cnt += hv[i];
        }
        unsigned long long mb = __ballot(Ti >= 0);
        int wl = __ffsll(mb) - 1;                 // unique crossing lane
        if (lane == wl) { s_T = lane * 16 + Ti; s_krem = kremi; s_kb = kbi; }
    }
    __syncthreads();                                             // B3
    const unsigned T = (unsigned)s_T;
    const int krem = s_krem;
    const bool ovf = s_kb > 272;                  // boundary-bin size known up front

    // scan 2: strict-selected -> nlist (<=63); boundary bin -> low hist (+ list if fits)
    ELEM_LOOP(
        unsigned bin = key >> 6;
        if (bin > T) { int p = atomicAdd(&nln, 1); nlist[p & 63] = (int)key; }
        else if (bin == T) {
            atomicAdd(&lowh[key & 63], 1);
            if (!ovf) { int p = atomicAdd(&bln, 1); if (p < 272) blist[p] = (int)key; }
        }
    )
    __syncthreads();                                             // B4

    // wave0: low digit within boundary bin
    if (wid == 0) {
        int a = lowh[lane];
        int s = a;
#pragma unroll
        for (int o = 1; o < 64; o <<= 1) {
            int v = __shfl_down(s, o);
            if (lane + o < 64) s += v;
        }
        const int E = s - a;
        unsigned long long mb = __ballot(E < krem && E + a >= krem);
        int wl = __ffsll(mb) - 1;
        if (lane == wl) { s_thr = (int)((T << 6) | (unsigned)lane); s_krem2 = krem - E; }
    }
    __syncthreads();                                             // B5
    const unsigned thr = (unsigned)s_thr;
    const int krem2 = s_krem2;

    float S = 0.f;
    if (ovf) {                                    // rare: boundary bin too big to compact
        float f = 0.f;
        ELEM_LOOP( if (key > thr) f += __expf(2.0f * bf2f(unkey(key))); )
#pragma unroll
        for (int o = 1; o < 64; o <<= 1) f += __shfl_xor(f, o);
        if (lane == 0) s_partial[wid] = f;
        __syncthreads();                                         // B6
        if (wid == 0) S = s_partial[0] + s_partial[1] + s_partial[2] + s_partial[3];
    } else if (wid == 0) {
        const int nc = nln;
        float f = (lane < nc) ? __expf(2.0f * bf2f(unkey((unsigned)nlist[lane]))) : 0.f;
        const int bc = bln;
        for (int s2 = lane; s2 < bc; s2 += 64) {
            unsigned k = (unsigned)blist[s2];
            if ((k & 63u) > (thr & 63u)) f += __expf(2.0f * bf2f(unkey(k)));
        }
#pragma unroll
        for (int o = 1; o < 64; o <<= 1) f += __shfl_xor(f, o);
        S = f;
    }
#undef ELEM_LOOP

    // wave0: ties + positives (direct gather via class list) + loss
    if (wid == 0) {
        S += (float)krem2 * __expf(2.0f * bf2f(unkey(thr)));
        const int o0 = off[ti], o1 = off[ti + 1];
        unsigned pk[8];
#pragma unroll
        for (int s2 = 0; s2 < 8; ++s2) {
            int idx = o0 + lane + s2 * 64;
            if (idx < o1) {
                unsigned key = srow[clist[idx]];
                pk[s2] = (key << 9) | ((unsigned)lane << 3) | (unsigned)s2;
            } else pk[s2] = 0xFFFFFFFFu;
        }
        float acc = 0.f;
#pragma unroll
        for (int r = 0; r < 8; ++r) {
            unsigned best = pk[0];
#pragma unroll
            for (int s2 = 1; s2 < 8; ++s2) best = best < pk[s2] ? best : pk[s2];
#pragma unroll
            for (int o = 1; o < 64; o <<= 1) {
                unsigned v = (unsigned)__shfl_xor((int)best, o);
                best = best < v ? best : v;
            }
            if (best != 0xFFFFFFFFu) {
                if (lane == (int)((best >> 3) & 63u)) pk[best & 7u] = 0xFFFFFFFFu;
                if (lane == 0) {
                    float p = bf2f(unkey(best >> 9));
                    acc += logf(__expf(2.0f * p) + S) - 2.0f * p;
                }
            }
        }
        if (lane == 0) out[row] = acc * 0.125f;
    }
}

extern "C" void kernel_launch(void* const* d_in, const int* in_sizes, int n_in,
                              void* d_out, int out_size, void* d_ws, size_t ws_size,
                              hipStream_t stream) {
    const float* newf = (const float*)d_in[1];
    const unsigned int* tgtw = (const unsigned int*)d_in[2];
    float* out = (float*)d_out;
    char* ws = (char*)d_ws;
    unsigned char* tgb = (unsigned char*)ws;                          // 8 KB
    unsigned int* cm2 = (unsigned int*)(ws + 8192);                   // 100 KB
    int* off = (int*)(ws + 110592);                                   // 1 KB (129 ints)
    unsigned short* clist = (unsigned short*)(ws + 111616);           // 16 KB
    unsigned short* nf = (unsigned short*)(ws + 131072);              // 8 MB (4K-aligned)
    unsigned short* simk = (unsigned short*)(ws + 131072 + (size_t)B_N * C_DIM * 2);

    size_t fixed = 131072 + (size_t)B_N * C_DIM * 2;
    size_t avail = (ws_size > fixed) ? (ws_size - fixed) : 0;
    long maxRows = (long)(avail / ((size_t)B_N * 2));
    int chunk = (int)((maxRows / 128) * 128);
    if (chunk < 128) chunk = 128;
    if (chunk > B_N) chunk = B_N;

    hipLaunchKernelGGL(prep_all, dim3(1), dim3(256), 0, stream, tgtw, tgb, clist, off);
    hipLaunchKernelGGL(class_masks, dim3(100), dim3(256), 0, stream, tgb, cm2);
    hipLaunchKernelGGL(normalize_k, dim3(B_N / 4), dim3(256), 0, stream, newf, nf);
    if (chunk == B_N) {
        hipLaunchKernelGGL(gemm_sim256, dim3(NTRI2), dim3(512), 0, stream, nf, simk);
        hipLaunchKernelGGL(select_loss, dim3(B_N), dim3(256), 0, stream,
                           simk, tgb, cm2, clist, off, out, 0);
    } else {
        for (int r0 = 0; r0 < B_N; r0 += chunk) {
            int rows = (B_N - r0 < chunk) ? (B_N - r0) : chunk;
            hipLaunchKernelGGL(gemm_sim, dim3(64, rows / 128), dim3(256), 0, stream,
                               nf, simk, r0);
            hipLaunchKernelGGL(select_loss, dim3(rows), dim3(256), 0, stream,
                               simk, tgb, cm2, clist, off, out, r0);
        }
    }
}

// Round 11
// 172.452 us; speedup vs baseline: 1.1824x; 1.1824x over previous
//
#include <hip/hip_runtime.h>
#include <hip/hip_bf16.h>

#define B_N 8192
#define C_DIM 512
#define NT 64            // 128-wide tiles per dimension
#define NTRI 2080        // NT*(NT+1)/2 upper-triangle tiles

typedef __attribute__((ext_vector_type(4))) float f32x4;
typedef __attribute__((ext_vector_type(8))) __bf16 bf16x8;
typedef __attribute__((address_space(3))) unsigned int lds_u32;
typedef const __attribute__((address_space(1))) unsigned int glb_u32;

__device__ __forceinline__ void gl_lds16(const unsigned short* g, unsigned short* l) {
    __builtin_amdgcn_global_load_lds((glb_u32*)g, (lds_u32*)l, 16, 0, 0);
}

__device__ __forceinline__ unsigned short f2bf(float f) {
    unsigned int u = __float_as_uint(f);
    u += 0x7FFFu + ((u >> 16) & 1u);          // RNE
    return (unsigned short)(u >> 16);
}
__device__ __forceinline__ float bf2f(unsigned int s) {
    return __uint_as_float(s << 16);
}
// order-preserving key: float order -> unsigned ascending. key 0 / 0xFFFF impossible for finite sims.
__device__ __forceinline__ unsigned negkey(unsigned ub) {
    return (ub & 0x8000u) ? ((~ub) & 0xFFFFu) : (ub | 0x8000u);
}
__device__ __forceinline__ unsigned unkey(unsigned k) {
    return (k & 0x8000u) ? (k ^ 0x8000u) : ((~k) & 0xFFFFu);
}

// ---- one-block prep: layout detect, class bytes, class member lists (counting sort) ----
__global__ void prep_all(const unsigned int* __restrict__ t, unsigned char* __restrict__ tgb,
                         unsigned short* __restrict__ clist, int* __restrict__ off) {
    __shared__ int bad, cnt[128], base[128];
    const int tid = threadIdx.x;
    if (tid == 0) bad = 0;
    if (tid < 128) cnt[tid] = 0;
    __syncthreads();
    int local = 0;
    for (int k = tid; k < 4096; k += 256)        // first 32KB only: safe for both layouts
        if (t[2 * k + 1] != 0u) local = 1;
    if (local) atomicOr(&bad, 1);
    __syncthreads();
    const int is64 = (bad == 0);
    for (int i = 0; i < 32; ++i) {
        int j = i * 256 + tid;
        unsigned c = (is64 ? t[2 * j] : t[j]) & 127u;   // classes < 100
        tgb[j] = (unsigned char)c;
        atomicAdd(&cnt[c], 1);
    }
    __syncthreads();
    if (tid == 0) {
        int s = 0;
        for (int c = 0; c < 128; ++c) { base[c] = s; off[c] = s; s += cnt[c]; }
        off[128] = s;
    }
    __syncthreads();
    for (int i = 0; i < 32; ++i) {
        int j = i * 256 + tid;
        unsigned c = (is64 ? t[2 * j] : t[j]) & 127u;
        int idx = atomicAdd(&base[c], 1);
        clist[idx] = (unsigned short)j;
    }
}

// ---- per-class membership words: cm2[c*256+t] bit (q*8+e) = (tgb[q*2048+t*8+e]==c) ----
__global__ void class_masks(const unsigned char* __restrict__ tgb,
                            unsigned int* __restrict__ cm2) {
    const int c = blockIdx.x, t = threadIdx.x;
    unsigned w = 0;
#pragma unroll
    for (int q = 0; q < 4; ++q) {
        const unsigned char* base = tgb + q * 2048 + t * 8;
        unsigned b = 0;
#pragma unroll
        for (int e = 0; e < 8; ++e)
            b |= ((unsigned)(base[e] == c)) << e;
        w |= b << (8 * q);
    }
    cm2[c * 256 + t] = w;
}

// ---- L2 normalize rows, emit bf16 ----
__global__ __launch_bounds__(256) void normalize_k(const float* __restrict__ x,
                                                   unsigned short* __restrict__ nf) {
    const int wid = threadIdx.x >> 6, lane = threadIdx.x & 63;
    const size_t row = (size_t)blockIdx.x * 4 + wid;
    const float4* xr = (const float4*)(x + row * C_DIM) + lane * 2;
    float4 a = xr[0], b = xr[1];
    float ss = a.x * a.x + a.y * a.y + a.z * a.z + a.w * a.w +
               b.x * b.x + b.y * b.y + b.z * b.z + b.w * b.w;
#pragma unroll
    for (int m = 1; m < 64; m <<= 1) ss += __shfl_xor(ss, m);
    float sc = 1.0f / fmaxf(sqrtf(ss), 1e-12f);
    union { unsigned short s[8]; int4 v; } o;
    o.s[0] = f2bf(a.x * sc); o.s[1] = f2bf(a.y * sc);
    o.s[2] = f2bf(a.z * sc); o.s[3] = f2bf(a.w * sc);
    o.s[4] = f2bf(b.x * sc); o.s[5] = f2bf(b.y * sc);
    o.s[6] = f2bf(b.z * sc); o.s[7] = f2bf(b.w * sc);
    *(int4*)(nf + row * C_DIM + lane * 8) = o.v;
}

// ---- sim keys = negkey(bf16(nf @ nf^T)), 128x128 tiles ----
// symmetric==1: compact 1D triangular grid (2080 blocks, row-major id order, no swizzle);
// epilogue fully vectorized via LDS bounces (row-major for direct, col-major for transpose).
__global__ __launch_bounds__(256) void gemm_sim(const unsigned short* __restrict__ nf,
                                                unsigned short* __restrict__ simk,
                                                int rowBase, int symmetric) {
    __shared__ unsigned short smem[128 * 136];          // 34816 B; As|Bs use 32768; Cs aliases
    unsigned short* As = smem;
    unsigned short* Bs = smem + 8192;
    int tI, tJ;
    if (symmetric) {
        const int idp = (NTRI - 1) - (int)blockIdx.x;   // row-major triangle order
        int u = (int)((sqrtf(8.0f * (float)idp + 1.0f) - 1.0f) * 0.5f);
        while (u * (u + 1) / 2 > idp) --u;
        while ((u + 1) * (u + 2) / 2 <= idp) ++u;
        const int v = idp - u * (u + 1) / 2;
        tI = (NT - 1) - u;
        tJ = (NT - 1) - v;
    } else {
        tI = blockIdx.y; tJ = blockIdx.x;
    }
    const int tid = threadIdx.x;
    const int wid = tid >> 6, lane = tid & 63;
    const int wm = wid >> 1, wn = wid & 1;
    const int gr = rowBase + tI * 128;
    const int gc = tJ * 128;
    f32x4 zero = {0.f, 0.f, 0.f, 0.f};
    f32x4 acc[4][4];
#pragma unroll
    for (int m = 0; m < 4; ++m)
#pragma unroll
        for (int n = 0; n < 4; ++n) acc[m][n] = zero;

    const int lr = lane >> 3, lcb = lane & 7;

    for (int k0 = 0; k0 < C_DIM; k0 += 64) {
#pragma unroll
        for (int i = 0; i < 4; ++i) {
            const int chunk = wid * 4 + i;
            const int r = chunk * 8 + lr;
            const int sc = (lcb ^ (r & 7)) << 3;        // inverse-swizzled source col
            gl_lds16(nf + (size_t)(gr + r) * C_DIM + k0 + sc, As + chunk * 512);
            gl_lds16(nf + (size_t)(gc + r) * C_DIM + k0 + sc, Bs + chunk * 512);
        }
        __syncthreads();
#pragma unroll
        for (int kk = 0; kk < 2; ++kk) {
            const int krow = kk * 32 + (lane >> 4) * 8;
            bf16x8 a[4], b[4];
#pragma unroll
            for (int m = 0; m < 4; ++m) {
                const int R = wm * 64 + m * 16 + (lane & 15);
                a[m] = *(const bf16x8*)&As[R * 64 + (krow ^ ((R & 7) << 3))];
            }
#pragma unroll
            for (int n = 0; n < 4; ++n) {
                const int R = wn * 64 + n * 16 + (lane & 15);
                b[n] = *(const bf16x8*)&Bs[R * 64 + (krow ^ ((R & 7) << 3))];
            }
#pragma unroll
            for (int m = 0; m < 4; ++m)
#pragma unroll
                for (int n = 0; n < 4; ++n)
                    acc[m][n] = __builtin_amdgcn_mfma_f32_16x16x32_bf16(a[m], b[n], acc[m][n], 0, 0, 0);
        }
        __syncthreads();                                 // also makes smem dead -> Cs reuse safe
    }

    // pre-pack keys once
    unsigned short kk4[4][4][4];
#pragma unroll
    for (int m = 0; m < 4; ++m)
#pragma unroll
        for (int n = 0; n < 4; ++n)
#pragma unroll
            for (int j = 0; j < 4; ++j)
                kk4[m][n][j] = (unsigned short)negkey(f2bf(acc[m][n][j]));

    unsigned short* Cs = smem;
    const int fc = (lane & 15);                          // fragment col-in-16
    const int fr = (lane >> 4) << 2;                     // fragment row base

    // ---- direct (row-major) write via row-major bounce: Cs[r][c], stride 136 ----
#pragma unroll
    for (int m = 0; m < 4; ++m)
#pragma unroll
        for (int n = 0; n < 4; ++n) {
            const int c = wn * 64 + n * 16 + fc;
            const int r0 = wm * 64 + m * 16 + fr;
#pragma unroll
            for (int j = 0; j < 4; ++j)
                Cs[(r0 + j) * 136 + c] = kk4[m][n][j];   // 2-way bank alias: free
        }
    __syncthreads();
#pragma unroll
    for (int k = 0; k < 8; ++k) {
        const int lin = tid + k * 256;                   // 0..2047
        const int r = lin >> 4;
        const int c0 = (lin & 15) * 8;
        int4 v = *(const int4*)&Cs[r * 136 + c0];
        *(int4*)&simk[(size_t)(gr - rowBase + r) * B_N + gc + c0] = v;
    }

    if (symmetric && tJ > tI) {
        // ---- transposed write via col-major bounce: Cs[c][r], stride 136 ----
        __syncthreads();
#pragma unroll
        for (int m = 0; m < 4; ++m)
#pragma unroll
            for (int n = 0; n < 4; ++n) {
                const int c = wn * 64 + n * 16 + fc;
                const int r0 = wm * 64 + m * 16 + fr;
                ushort4 pk;
                pk.x = kk4[m][n][0]; pk.y = kk4[m][n][1];
                pk.z = kk4[m][n][2]; pk.w = kk4[m][n][3];
                *(ushort4*)&Cs[c * 136 + r0] = pk;
            }
        __syncthreads();
#pragma unroll
        for (int k = 0; k < 8; ++k) {
            const int lin = tid + k * 256;
            const int c = lin >> 4;
            const int r0 = (lin & 15) * 8;
            int4 v = *(const int4*)&Cs[c * 136 + r0];
            *(int4*)&simk[(size_t)(gc + c) * B_N + gr + r0] = v;
        }
    }
}

// ---- block-per-row selection + loss: premasked keys, 1024-bin hist, 2 scans ----
__global__ __launch_bounds__(256) void select_loss(const unsigned short* __restrict__ simk,
                                                   const unsigned char* __restrict__ tgb,
                                                   const unsigned int* __restrict__ cm2,
                                                   const unsigned short* __restrict__ clist,
                                                   const int* __restrict__ off,
                                                   float* __restrict__ out, int rowBase) {
    __shared__ int hG[2080];          // 2 groups x 1040 (1024 bins + pad bin>>6)
    __shared__ int lowh[64];
    __shared__ int nlist[64];
    __shared__ int blist[272];
    __shared__ float s_partial[4];
    __shared__ int s_T, s_krem, s_kb, s_thr, s_krem2, nln, bln;

    const int tid = threadIdx.x;
    const int wid = tid >> 6, lane = tid & 63;
    const int row = rowBase + blockIdx.x;
    const unsigned short* srow = simk + (size_t)blockIdx.x * B_N;
    const int ti = tgb[row];

    int4 A[4];
    const unsigned m = cm2[ti * 256 + tid];
#pragma unroll
    for (int q = 0; q < 4; ++q) {
        A[q] = *(const int4*)(srow + q * 2048 + tid * 8);
#pragma unroll
        for (int d = 0; d < 4; ++d) {
            unsigned two = (m >> (q * 8 + d * 2)) & 3u;
            unsigned kill = ((two & 1u) * 0xFFFFu) | (((two >> 1) & 1u) * 0xFFFF0000u);
            int v = (d == 0 ? A[q].x : d == 1 ? A[q].y : d == 2 ? A[q].z : A[q].w);
            v = (int)((unsigned)v & ~kill);
            if (d == 0) A[q].x = v; else if (d == 1) A[q].y = v;
            else if (d == 2) A[q].z = v; else A[q].w = v;
        }
    }

    for (int i = tid; i < 2080; i += 256) hG[i] = 0;
    if (tid < 64) lowh[tid] = 0;
    if (tid == 0) { nln = 0; bln = 0; }
    __syncthreads();                                             // B1

#define ELEM_LOOP(BODY)                                                          \
    _Pragma("unroll")                                                            \
    for (int q = 0; q < 4; ++q) {                                                \
        _Pragma("unroll")                                                        \
        for (int d = 0; d < 4; ++d) {                                            \
            unsigned w32 = (unsigned)(d == 0 ? A[q].x : d == 1 ? A[q].y          \
                                    : d == 2 ? A[q].z : A[q].w);                 \
            _Pragma("unroll")                                                    \
            for (int h2 = 0; h2 < 2; ++h2) {                                     \
                unsigned key = h2 ? (w32 >> 16) : (w32 & 0xFFFFu);               \
                BODY                                                             \
            }                                                                    \
        }                                                                        \
    }

    // scan 1: unconditional 1024-bin hist (half-wave groups, padded addressing)
    int* hGg = hG + ((tid >> 5) & 1) * 1040;
    ELEM_LOOP(
        unsigned bin = key >> 6;
        atomicAdd(&hGg[bin + (bin >> 6)], 1);
    )
    __syncthreads();                                             // B2

    // wave0: find threshold bin T (top-64) over 1024 bins
    if (wid == 0) {
        int hv[16]; int tl = 0;
#pragma unroll
        for (int i = 0; i < 16; ++i) {
            int b = lane * 16 + i;
            int a = hG[b + (b >> 6)] + hG[1040 + b + (b >> 6)];
            hv[i] = a; tl += a;
        }
        int s = tl;
#pragma unroll
        for (int o = 1; o < 64; o <<= 1) {
            int v = __shfl_down(s, o);
            if (lane + o < 64) s += v;
        }
        const int E = s - tl;                    // sum over lanes above
        int cnt = E, Ti = -1, kremi = 0, kbi = 0;
#pragma unroll
        for (int i = 15; i >= 0; --i) {
            bool cross = (cnt < 64) && (cnt + hv[i] >= 64);
            if (cross) { Ti = i; kremi = 64 - cnt; kbi = hv[i]; }
            cnt += hv[i];
        }
        unsigned long long mb = __ballot(Ti >= 0);
        int wl = __ffsll(mb) - 1;                 // unique crossing lane
        if (lane == wl) { s_T = lane * 16 + Ti; s_krem = kremi; s_kb = kbi; }
    }
    __syncthreads();                                             // B3
    const unsigned T = (unsigned)s_T;
    const int krem = s_krem;
    const bool ovf = s_kb > 272;                  // boundary-bin size known up front

    // scan 2: strict-selected -> nlist (<=63); boundary bin -> low hist (+ list if fits)
    ELEM_LOOP(
        unsigned bin = key >> 6;
        if (bin > T) { int p = atomicAdd(&nln, 1); nlist[p & 63] = (int)key; }
        else if (bin == T) {
            atomicAdd(&lowh[key & 63], 1);
            if (!ovf) { int p = atomicAdd(&bln, 1); if (p < 272) blist[p] = (int)key; }
        }
    )
    __syncthreads();                                             // B4

    // wave0: low digit within boundary bin
    if (wid == 0) {
        int a = lowh[lane];
        int s = a;
#pragma unroll
        for (int o = 1; o < 64; o <<= 1) {
            int v = __shfl_down(s, o);
            if (lane + o < 64) s += v;
        }
        const int E = s - a;
        unsigned long long mb = __ballot(E < krem && E + a >= krem);
        int wl = __ffsll(mb) - 1;
        if (lane == wl) { s_thr = (int)((T << 6) | (unsigned)lane); s_krem2 = krem - E; }
    }
    __syncthreads();                                             // B5
    const unsigned thr = (unsigned)s_thr;
    const int krem2 = s_krem2;

    float S = 0.f;
    if (ovf) {                                    // rare: boundary bin too big to compact
        float f = 0.f;
        ELEM_LOOP( if (key > thr) f += __expf(2.0f * bf2f(unkey(key))); )
#pragma unroll
        for (int o = 1; o < 64; o <<= 1) f += __shfl_xor(f, o);
        if (lane == 0) s_partial[wid] = f;
        __syncthreads();                                         // B6
        if (wid == 0) S = s_partial[0] + s_partial[1] + s_partial[2] + s_partial[3];
    } else if (wid == 0) {
        const int nc = nln;
        float f = (lane < nc) ? __expf(2.0f * bf2f(unkey((unsigned)nlist[lane]))) : 0.f;
        const int bc = bln;
        for (int s2 = lane; s2 < bc; s2 += 64) {
            unsigned k = (unsigned)blist[s2];
            if ((k & 63u) > (thr & 63u)) f += __expf(2.0f * bf2f(unkey(k)));
        }
#pragma unroll
        for (int o = 1; o < 64; o <<= 1) f += __shfl_xor(f, o);
        S = f;
    }
#undef ELEM_LOOP

    // wave0: ties + positives (direct gather via class list) + loss
    if (wid == 0) {
        S += (float)krem2 * __expf(2.0f * bf2f(unkey(thr)));
        const int o0 = off[ti], o1 = off[ti + 1];
        unsigned pk[8];
#pragma unroll
        for (int s2 = 0; s2 < 8; ++s2) {
            int idx = o0 + lane + s2 * 64;
            if (idx < o1) {
                unsigned key = srow[clist[idx]];
                pk[s2] = (key << 9) | ((unsigned)lane << 3) | (unsigned)s2;
            } else pk[s2] = 0xFFFFFFFFu;
        }
        float acc = 0.f;
#pragma unroll
        for (int r = 0; r < 8; ++r) {
            unsigned best = pk[0];
#pragma unroll
            for (int s2 = 1; s2 < 8; ++s2) best = best < pk[s2] ? best : pk[s2];
#pragma unroll
            for (int o = 1; o < 64; o <<= 1) {
                unsigned v = (unsigned)__shfl_xor((int)best, o);
                best = best < v ? best : v;
            }
            if (best != 0xFFFFFFFFu) {
                if (lane == (int)((best >> 3) & 63u)) pk[best & 7u] = 0xFFFFFFFFu;
                if (lane == 0) {
                    float p = bf2f(unkey(best >> 9));
                    acc += logf(__expf(2.0f * p) + S) - 2.0f * p;
                }
            }
        }
        if (lane == 0) out[row] = acc * 0.125f;
    }
}

extern "C" void kernel_launch(void* const* d_in, const int* in_sizes, int n_in,
                              void* d_out, int out_size, void* d_ws, size_t ws_size,
                              hipStream_t stream) {
    const float* newf = (const float*)d_in[1];
    const unsigned int* tgtw = (const unsigned int*)d_in[2];
    float* out = (float*)d_out;
    char* ws = (char*)d_ws;
    unsigned char* tgb = (unsigned char*)ws;                          // 8 KB
    unsigned int* cm2 = (unsigned int*)(ws + 8192);                   // 100 KB
    int* off = (int*)(ws + 110592);                                   // 1 KB (129 ints)
    unsigned short* clist = (unsigned short*)(ws + 111616);           // 16 KB
    unsigned short* nf = (unsigned short*)(ws + 131072);              // 8 MB (4K-aligned)
    unsigned short* simk = (unsigned short*)(ws + 131072 + (size_t)B_N * C_DIM * 2);

    size_t fixed = 131072 + (size_t)B_N * C_DIM * 2;
    size_t avail = (ws_size > fixed) ? (ws_size - fixed) : 0;
    long maxRows = (long)(avail / ((size_t)B_N * 2));
    int chunk = (int)((maxRows / 128) * 128);
    if (chunk < 128) chunk = 128;
    if (chunk > B_N) chunk = B_N;

    hipLaunchKernelGGL(prep_all, dim3(1), dim3(256), 0, stream, tgtw, tgb, clist, off);
    hipLaunchKernelGGL(class_masks, dim3(100), dim3(256), 0, stream, tgb, cm2);
    hipLaunchKernelGGL(normalize_k, dim3(B_N / 4), dim3(256), 0, stream, newf, nf);
    if (chunk == B_N) {
        hipLaunchKernelGGL(gemm_sim, dim3(NTRI), dim3(256), 0, stream, nf, simk, 0, 1);
        hipLaunchKernelGGL(select_loss, dim3(B_N), dim3(256), 0, stream,
                           simk, tgb, cm2, clist, off, out, 0);
    } else {
        for (int r0 = 0; r0 < B_N; r0 += chunk) {
            int rows = (B_N - r0 < chunk) ? (B_N - r0) : chunk;
            hipLaunchKernelGGL(gemm_sim, dim3(64, rows / 128), dim3(256), 0, stream,
                               nf, simk, r0, 0);
            hipLaunchKernelGGL(select_loss, dim3(rows), dim3(256), 0, stream,
                               simk, tgb, cm2, clist, off, out, r0);
        }
    }
}

// Round 12
// 169.525 us; speedup vs baseline: 1.2028x; 1.0173x over previous
//
#include <hip/hip_runtime.h>
#include <hip/hip_bf16.h>

#define B_N 8192
#define C_DIM 512
#define NT 64            // 128-wide tiles per dimension
#define NTRI 2080        // NT*(NT+1)/2 upper-triangle tiles

typedef __attribute__((ext_vector_type(4))) float f32x4;
typedef __attribute__((ext_vector_type(8))) __bf16 bf16x8;
typedef __attribute__((address_space(3))) unsigned int lds_u32;
typedef const __attribute__((address_space(1))) unsigned int glb_u32;

__device__ __forceinline__ void gl_lds16(const unsigned short* g, unsigned short* l) {
    __builtin_amdgcn_global_load_lds((glb_u32*)g, (lds_u32*)l, 16, 0, 0);
}

__device__ __forceinline__ unsigned short f2bf(float f) {
    unsigned int u = __float_as_uint(f);
    u += 0x7FFFu + ((u >> 16) & 1u);          // RNE
    return (unsigned short)(u >> 16);
}
__device__ __forceinline__ float bf2f(unsigned int s) {
    return __uint_as_float(s << 16);
}
// order-preserving key: float order -> unsigned ascending. key 0 / 0xFFFF impossible for finite sims.
__device__ __forceinline__ unsigned negkey(unsigned ub) {
    return (ub & 0x8000u) ? ((~ub) & 0xFFFFu) : (ub | 0x8000u);
}
__device__ __forceinline__ unsigned unkey(unsigned k) {
    return (k & 0x8000u) ? (k ^ 0x8000u) : ((~k) & 0xFFFFu);
}

// suffix-scan crossing: per-lane count c, budget krem -> threshold lane wl (unique),
// all lanes get (digit=wl, krem_out = krem - E_wl, cnt_at = c_wl)
__device__ __forceinline__ void cross64(int c, int lane, int krem,
                                        int& digit, int& krem_out, int& cnt_at) {
    int s = c;
#pragma unroll
    for (int o = 1; o < 64; o <<= 1) {
        int t = __shfl_down(s, o);
        if (lane + o < 64) s += t;
    }
    const int E = s - c;                          // suffix over strictly-higher lanes
    unsigned long long mb = __ballot(E < krem && E + c >= krem);
    int wl = __ffsll(mb) - 1;                     // unique crossing lane
    digit = wl;
    krem_out = __shfl(krem - E, wl);
    cnt_at = __shfl(c, wl);
}

// ---- one-block prep: layout detect, class bytes, class member lists (counting sort) ----
__global__ void prep_all(const unsigned int* __restrict__ t, unsigned char* __restrict__ tgb,
                         unsigned short* __restrict__ clist, int* __restrict__ off) {
    __shared__ int bad, cnt[128], base[128];
    const int tid = threadIdx.x;
    if (tid == 0) bad = 0;
    if (tid < 128) cnt[tid] = 0;
    __syncthreads();
    int local = 0;
    for (int k = tid; k < 4096; k += 256)        // first 32KB only: safe for both layouts
        if (t[2 * k + 1] != 0u) local = 1;
    if (local) atomicOr(&bad, 1);
    __syncthreads();
    const int is64 = (bad == 0);
    for (int i = 0; i < 32; ++i) {
        int j = i * 256 + tid;
        unsigned c = (is64 ? t[2 * j] : t[j]) & 127u;   // classes < 100
        tgb[j] = (unsigned char)c;
        atomicAdd(&cnt[c], 1);
    }
    __syncthreads();
    if (tid == 0) {
        int s = 0;
        for (int c = 0; c < 128; ++c) { base[c] = s; off[c] = s; s += cnt[c]; }
        off[128] = s;
    }
    __syncthreads();
    for (int i = 0; i < 32; ++i) {
        int j = i * 256 + tid;
        unsigned c = (is64 ? t[2 * j] : t[j]) & 127u;
        int idx = atomicAdd(&base[c], 1);
        clist[idx] = (unsigned short)j;
    }
}

// ---- per-class membership words: cm2[c*256+t] bit (q*8+e) = (tgb[q*2048+t*8+e]==c) ----
__global__ void class_masks(const unsigned char* __restrict__ tgb,
                            unsigned int* __restrict__ cm2) {
    const int c = blockIdx.x, t = threadIdx.x;
    unsigned w = 0;
#pragma unroll
    for (int q = 0; q < 4; ++q) {
        const unsigned char* base = tgb + q * 2048 + t * 8;
        unsigned b = 0;
#pragma unroll
        for (int e = 0; e < 8; ++e)
            b |= ((unsigned)(base[e] == c)) << e;
        w |= b << (8 * q);
    }
    cm2[c * 256 + t] = w;
}

// ---- L2 normalize rows, emit bf16 ----
__global__ __launch_bounds__(256) void normalize_k(const float* __restrict__ x,
                                                   unsigned short* __restrict__ nf) {
    const int wid = threadIdx.x >> 6, lane = threadIdx.x & 63;
    const size_t row = (size_t)blockIdx.x * 4 + wid;
    const float4* xr = (const float4*)(x + row * C_DIM) + lane * 2;
    float4 a = xr[0], b = xr[1];
    float ss = a.x * a.x + a.y * a.y + a.z * a.z + a.w * a.w +
               b.x * b.x + b.y * b.y + b.z * b.z + b.w * b.w;
#pragma unroll
    for (int m = 1; m < 64; m <<= 1) ss += __shfl_xor(ss, m);
    float sc = 1.0f / fmaxf(sqrtf(ss), 1e-12f);
    union { unsigned short s[8]; int4 v; } o;
    o.s[0] = f2bf(a.x * sc); o.s[1] = f2bf(a.y * sc);
    o.s[2] = f2bf(a.z * sc); o.s[3] = f2bf(a.w * sc);
    o.s[4] = f2bf(b.x * sc); o.s[5] = f2bf(b.y * sc);
    o.s[6] = f2bf(b.z * sc); o.s[7] = f2bf(b.w * sc);
    *(int4*)(nf + row * C_DIM + lane * 8) = o.v;
}

// ---- sim keys = negkey(bf16(nf @ nf^T)), 128x128 tiles (R11 structure, unchanged) ----
__global__ __launch_bounds__(256) void gemm_sim(const unsigned short* __restrict__ nf,
                                                unsigned short* __restrict__ simk,
                                                int rowBase, int symmetric) {
    __shared__ unsigned short smem[128 * 136];
    unsigned short* As = smem;
    unsigned short* Bs = smem + 8192;
    int tI, tJ;
    if (symmetric) {
        const int idp = (NTRI - 1) - (int)blockIdx.x;   // row-major triangle order
        int u = (int)((sqrtf(8.0f * (float)idp + 1.0f) - 1.0f) * 0.5f);
        while (u * (u + 1) / 2 > idp) --u;
        while ((u + 1) * (u + 2) / 2 <= idp) ++u;
        const int v = idp - u * (u + 1) / 2;
        tI = (NT - 1) - u;
        tJ = (NT - 1) - v;
    } else {
        tI = blockIdx.y; tJ = blockIdx.x;
    }
    const int tid = threadIdx.x;
    const int wid = tid >> 6, lane = tid & 63;
    const int wm = wid >> 1, wn = wid & 1;
    const int gr = rowBase + tI * 128;
    const int gc = tJ * 128;
    f32x4 zero = {0.f, 0.f, 0.f, 0.f};
    f32x4 acc[4][4];
#pragma unroll
    for (int m = 0; m < 4; ++m)
#pragma unroll
        for (int n = 0; n < 4; ++n) acc[m][n] = zero;

    const int lr = lane >> 3, lcb = lane & 7;

    for (int k0 = 0; k0 < C_DIM; k0 += 64) {
#pragma unroll
        for (int i = 0; i < 4; ++i) {
            const int chunk = wid * 4 + i;
            const int r = chunk * 8 + lr;
            const int sc = (lcb ^ (r & 7)) << 3;
            gl_lds16(nf + (size_t)(gr + r) * C_DIM + k0 + sc, As + chunk * 512);
            gl_lds16(nf + (size_t)(gc + r) * C_DIM + k0 + sc, Bs + chunk * 512);
        }
        __syncthreads();
#pragma unroll
        for (int kk = 0; kk < 2; ++kk) {
            const int krow = kk * 32 + (lane >> 4) * 8;
            bf16x8 a[4], b[4];
#pragma unroll
            for (int m = 0; m < 4; ++m) {
                const int R = wm * 64 + m * 16 + (lane & 15);
                a[m] = *(const bf16x8*)&As[R * 64 + (krow ^ ((R & 7) << 3))];
            }
#pragma unroll
            for (int n = 0; n < 4; ++n) {
                const int R = wn * 64 + n * 16 + (lane & 15);
                b[n] = *(const bf16x8*)&Bs[R * 64 + (krow ^ ((R & 7) << 3))];
            }
#pragma unroll
            for (int m = 0; m < 4; ++m)
#pragma unroll
                for (int n = 0; n < 4; ++n)
                    acc[m][n] = __builtin_amdgcn_mfma_f32_16x16x32_bf16(a[m], b[n], acc[m][n], 0, 0, 0);
        }
        __syncthreads();
    }

    unsigned short kk4[4][4][4];
#pragma unroll
    for (int m = 0; m < 4; ++m)
#pragma unroll
        for (int n = 0; n < 4; ++n)
#pragma unroll
            for (int j = 0; j < 4; ++j)
                kk4[m][n][j] = (unsigned short)negkey(f2bf(acc[m][n][j]));

    unsigned short* Cs = smem;
    const int fc = (lane & 15);
    const int fr = (lane >> 4) << 2;

#pragma unroll
    for (int m = 0; m < 4; ++m)
#pragma unroll
        for (int n = 0; n < 4; ++n) {
            const int c = wn * 64 + n * 16 + fc;
            const int r0 = wm * 64 + m * 16 + fr;
#pragma unroll
            for (int j = 0; j < 4; ++j)
                Cs[(r0 + j) * 136 + c] = kk4[m][n][j];
        }
    __syncthreads();
#pragma unroll
    for (int k = 0; k < 8; ++k) {
        const int lin = tid + k * 256;
        const int r = lin >> 4;
        const int c0 = (lin & 15) * 8;
        int4 v = *(const int4*)&Cs[r * 136 + c0];
        *(int4*)&simk[(size_t)(gr - rowBase + r) * B_N + gc + c0] = v;
    }

    if (symmetric && tJ > tI) {
        __syncthreads();
#pragma unroll
        for (int m = 0; m < 4; ++m)
#pragma unroll
            for (int n = 0; n < 4; ++n) {
                const int c = wn * 64 + n * 16 + fc;
                const int r0 = wm * 64 + m * 16 + fr;
                ushort4 pk;
                pk.x = kk4[m][n][0]; pk.y = kk4[m][n][1];
                pk.z = kk4[m][n][2]; pk.w = kk4[m][n][3];
                *(ushort4*)&Cs[c * 136 + r0] = pk;
            }
        __syncthreads();
#pragma unroll
        for (int k = 0; k < 8; ++k) {
            const int lin = tid + k * 256;
            const int c = lin >> 4;
            const int r0 = (lin & 15) * 8;
            int4 v = *(const int4*)&Cs[c * 136 + r0];
            *(int4*)&simk[(size_t)(gc + c) * B_N + gr + r0] = v;
        }
    }
}

// ---- block-per-row selection + loss: 3-level (6/6/4-bit) radix, conflict-lite hists ----
__global__ __launch_bounds__(256) void select_loss(const unsigned short* __restrict__ simk,
                                                   const unsigned char* __restrict__ tgb,
                                                   const unsigned int* __restrict__ cm2,
                                                   const unsigned short* __restrict__ clist,
                                                   const int* __restrict__ off,
                                                   float* __restrict__ out, int rowBase) {
    __shared__ __align__(16) int hA[64 * 17];     // bin*17 + (tid&15): <=4-way same-addr
    __shared__ __align__(16) int hB[64 * 17];
    __shared__ int lowh16[16];
    __shared__ int nlist[64];
    __shared__ int blist[512];
    __shared__ float s_partial[4];
    __shared__ int nln, bln;

    const int tid = threadIdx.x;
    const int wid = tid >> 6, lane = tid & 63;
    const int g = tid & 15;
    const int row = rowBase + blockIdx.x;
    const unsigned short* srow = simk + (size_t)blockIdx.x * B_N;
    const int ti = tgb[row];

    // load 32 keys, mask same-class halves to 0 (never selected: negatives occupy bins>0)
    int4 A[4];
    const unsigned m = cm2[ti * 256 + tid];
#pragma unroll
    for (int q = 0; q < 4; ++q) {
        A[q] = *(const int4*)(srow + q * 2048 + tid * 8);
#pragma unroll
        for (int d = 0; d < 4; ++d) {
            unsigned two = (m >> (q * 8 + d * 2)) & 3u;
            unsigned kill = ((two & 1u) * 0xFFFFu) | (((two >> 1) & 1u) * 0xFFFF0000u);
            int v = (d == 0 ? A[q].x : d == 1 ? A[q].y : d == 2 ? A[q].z : A[q].w);
            v = (int)((unsigned)v & ~kill);
            if (d == 0) A[q].x = v; else if (d == 1) A[q].y = v;
            else if (d == 2) A[q].z = v; else A[q].w = v;
        }
    }

    // wave0: prefetch positive keys early (latency hides under the scans)
    const int o0 = off[ti], o1 = off[ti + 1];
    unsigned pk[8];
    if (wid == 0) {
#pragma unroll
        for (int s2 = 0; s2 < 8; ++s2) {
            int idx = o0 + lane + s2 * 64;
            pk[s2] = (idx < o1)
                ? ((((unsigned)srow[clist[idx]]) << 9) | ((unsigned)lane << 3) | (unsigned)s2)
                : 0xFFFFFFFFu;
        }
    }

    // zero hists (272 int4 per buffer)
    {
        int4 z4 = {0, 0, 0, 0};
        for (int i = tid; i < 272; i += 256) { ((int4*)hA)[i] = z4; ((int4*)hB)[i] = z4; }
        if (tid < 16) lowh16[tid] = 0;
        if (tid == 0) { nln = 0; bln = 0; }
    }
    __syncthreads();                                             // B1

#define ELEM_LOOP(BODY)                                                          \
    _Pragma("unroll")                                                            \
    for (int q = 0; q < 4; ++q) {                                                \
        _Pragma("unroll")                                                        \
        for (int d = 0; d < 4; ++d) {                                            \
            unsigned w32 = (unsigned)(d == 0 ? A[q].x : d == 1 ? A[q].y          \
                                    : d == 2 ? A[q].z : A[q].w);                 \
            _Pragma("unroll")                                                    \
            for (int h2 = 0; h2 < 2; ++h2) {                                     \
                unsigned key = h2 ? (w32 >> 16) : (w32 & 0xFFFFu);               \
                BODY                                                             \
            }                                                                    \
        }                                                                        \
    }

    // scan 1: level-1 hist (bits 15..10)
    ELEM_LOOP( atomicAdd(&hA[(key >> 10) * 17 + g], 1); )
    __syncthreads();                                             // B2

    // all waves: level-1 threshold (lane = bin)
    int T1, krem1, kb1;
    {
        int c = 0;
#pragma unroll
        for (int r = 0; r < 16; ++r) c += hA[lane * 17 + r];
        cross64(c, lane, 64, T1, krem1, kb1);
    }
    const unsigned T1u = (unsigned)T1;

    // scan 2: level-2 hist (bits 9..4) within T1
    ELEM_LOOP( if ((key >> 10) == T1u) atomicAdd(&hB[((key >> 4) & 63u) * 17 + g], 1); )
    __syncthreads();                                             // B3

    int T2, krem2, kb2;
    {
        int c = 0;
#pragma unroll
        for (int r = 0; r < 16; ++r) c += hB[lane * 17 + r];
        cross64(c, lane, krem1, T2, krem2, kb2);
    }
    const unsigned P12 = (T1u << 6) | (unsigned)T2;
    const bool ovf = kb2 > 512;

    // scan 3: strict-above -> nlist (<=63); boundary prefix -> low hist (+ list if fits)
    ELEM_LOOP(
        unsigned hi12 = key >> 4;
        if (hi12 > P12) { int p = atomicAdd(&nln, 1); nlist[p & 63] = (int)key; }
        else if (hi12 == P12) {
            atomicAdd(&lowh16[key & 15u], 1);
            if (!ovf) { int p = atomicAdd(&bln, 1); if (p < 512) blist[p] = (int)key; }
        }
    )
    __syncthreads();                                             // B4

    // all waves: level-3 threshold (lane<16 = low nibble)
    int v3, kremf, kb3;
    {
        int c = (lane < 16) ? lowh16[lane] : 0;
        cross64(c, lane, krem2, v3, kremf, kb3);
    }
    const unsigned thr = (P12 << 4) | (unsigned)v3;

    float S = 0.f;
    if (ovf) {                                    // rare: boundary prefix too big to compact
        float f = 0.f;
        ELEM_LOOP( if (key > thr) f += __expf(2.0f * bf2f(unkey(key))); )
#pragma unroll
        for (int o = 1; o < 64; o <<= 1) f += __shfl_xor(f, o);
        if (lane == 0) s_partial[wid] = f;
        __syncthreads();                                         // B5 (block-uniform path)
        if (wid == 0) S = s_partial[0] + s_partial[1] + s_partial[2] + s_partial[3];
    } else if (wid == 0) {
        const int nc = nln;                       // <= 63 provably
        float f = (lane < nc) ? __expf(2.0f * bf2f(unkey((unsigned)nlist[lane]))) : 0.f;
        const int bc = bln;
        for (int s2 = lane; s2 < bc; s2 += 64) {
            unsigned k = (unsigned)blist[s2];
            if (k > thr) f += __expf(2.0f * bf2f(unkey(k)));
        }
#pragma unroll
        for (int o = 1; o < 64; o <<= 1) f += __shfl_xor(f, o);
        S = f;
    }
#undef ELEM_LOOP

    // wave0: ties + positives (prefetched) + loss
    if (wid == 0) {
        S += (float)kremf * __expf(2.0f * bf2f(unkey(thr)));
        float acc = 0.f;
#pragma unroll
        for (int r = 0; r < 8; ++r) {
            unsigned best = pk[0];
#pragma unroll
            for (int s2 = 1; s2 < 8; ++s2) best = best < pk[s2] ? best : pk[s2];
#pragma unroll
            for (int o = 1; o < 64; o <<= 1) {
                unsigned v = (unsigned)__shfl_xor((int)best, o);
                best = best < v ? best : v;
            }
            if (best != 0xFFFFFFFFu) {
                if (lane == (int)((best >> 3) & 63u)) pk[best & 7u] = 0xFFFFFFFFu;
                if (lane == 0) {
                    float p = bf2f(unkey(best >> 9));
                    acc += logf(__expf(2.0f * p) + S) - 2.0f * p;
                }
            }
        }
        if (lane == 0) out[row] = acc * 0.125f;
    }
}

extern "C" void kernel_launch(void* const* d_in, const int* in_sizes, int n_in,
                              void* d_out, int out_size, void* d_ws, size_t ws_size,
                              hipStream_t stream) {
    const float* newf = (const float*)d_in[1];
    const unsigned int* tgtw = (const unsigned int*)d_in[2];
    float* out = (float*)d_out;
    char* ws = (char*)d_ws;
    unsigned char* tgb = (unsigned char*)ws;                          // 8 KB
    unsigned int* cm2 = (unsigned int*)(ws + 8192);                   // 100 KB
    int* off = (int*)(ws + 110592);                                   // 1 KB (129 ints)
    unsigned short* clist = (unsigned short*)(ws + 111616);           // 16 KB
    unsigned short* nf = (unsigned short*)(ws + 131072);              // 8 MB (4K-aligned)
    unsigned short* simk = (unsigned short*)(ws + 131072 + (size_t)B_N * C_DIM * 2);

    size_t fixed = 131072 + (size_t)B_N * C_DIM * 2;
    size_t avail = (ws_size > fixed) ? (ws_size - fixed) : 0;
    long maxRows = (long)(avail / ((size_t)B_N * 2));
    int chunk = (int)((maxRows / 128) * 128);
    if (chunk < 128) chunk = 128;
    if (chunk > B_N) chunk = B_N;

    hipLaunchKernelGGL(prep_all, dim3(1), dim3(256), 0, stream, tgtw, tgb, clist, off);
    hipLaunchKernelGGL(class_masks, dim3(100), dim3(256), 0, stream, tgb, cm2);
    hipLaunchKernelGGL(normalize_k, dim3(B_N / 4), dim3(256), 0, stream, newf, nf);
    if (chunk == B_N) {
        hipLaunchKernelGGL(gemm_sim, dim3(NTRI), dim3(256), 0, stream, nf, simk, 0, 1);
        hipLaunchKernelGGL(select_loss, dim3(B_N), dim3(256), 0, stream,
                           simk, tgb, cm2, clist, off, out, 0);
    } else {
        for (int r0 = 0; r0 < B_N; r0 += chunk) {
            int rows = (B_N - r0 < chunk) ? (B_N - r0) : chunk;
            hipLaunchKernelGGL(gemm_sim, dim3(64, rows / 128), dim3(256), 0, stream,
                               nf, simk, r0, 0);
            hipLaunchKernelGGL(select_loss, dim3(rows), dim3(256), 0, stream,
                               simk, tgb, cm2, clist, off, out, r0);
        }
    }
}

// Round 13
// 144.684 us; speedup vs baseline: 1.4093x; 1.1717x over previous
//
#include <hip/hip_runtime.h>
#include <hip/hip_bf16.h>

#define B_N 8192
#define C_DIM 512
#define NT 64            // 128-wide tiles per dimension
#define NTRI 2080        // NT*(NT+1)/2 upper-triangle tiles
#define TGKEY 0xBDC0u    // negkey(bf16 0.09375): conservative top-64 pre-threshold

typedef __attribute__((ext_vector_type(4))) float f32x4;
typedef __attribute__((ext_vector_type(8))) __bf16 bf16x8;
typedef __attribute__((address_space(3))) unsigned int lds_u32;
typedef const __attribute__((address_space(1))) unsigned int glb_u32;

__device__ __forceinline__ void gl_lds16(const unsigned short* g, unsigned short* l) {
    __builtin_amdgcn_global_load_lds((glb_u32*)g, (lds_u32*)l, 16, 0, 0);
}

__device__ __forceinline__ unsigned short f2bf(float f) {
    unsigned int u = __float_as_uint(f);
    u += 0x7FFFu + ((u >> 16) & 1u);          // RNE
    return (unsigned short)(u >> 16);
}
__device__ __forceinline__ float bf2f(unsigned int s) {
    return __uint_as_float(s << 16);
}
// order-preserving key: float order -> unsigned ascending. key 0 impossible for finite sims.
__device__ __forceinline__ unsigned negkey(unsigned ub) {
    return (ub & 0x8000u) ? ((~ub) & 0xFFFFu) : (ub | 0x8000u);
}
__device__ __forceinline__ unsigned unkey(unsigned k) {
    return (k & 0x8000u) ? (k ^ 0x8000u) : ((~k) & 0xFFFFu);
}

// ---- one-block prep: layout detect, class bytes, class member lists (counting sort) ----
__global__ void prep_all(const unsigned int* __restrict__ t, unsigned char* __restrict__ tgb,
                         unsigned short* __restrict__ clist, int* __restrict__ off) {
    __shared__ int bad, cnt[128], base[128];
    const int tid = threadIdx.x;
    if (tid == 0) bad = 0;
    if (tid < 128) cnt[tid] = 0;
    __syncthreads();
    int local = 0;
    for (int k = tid; k < 4096; k += 256)        // first 32KB only: safe for both layouts
        if (t[2 * k + 1] != 0u) local = 1;
    if (local) atomicOr(&bad, 1);
    __syncthreads();
    const int is64 = (bad == 0);
    for (int i = 0; i < 32; ++i) {
        int j = i * 256 + tid;
        unsigned c = (is64 ? t[2 * j] : t[j]) & 127u;   // classes < 100
        tgb[j] = (unsigned char)c;
        atomicAdd(&cnt[c], 1);
    }
    __syncthreads();
    if (tid == 0) {
        int s = 0;
        for (int c = 0; c < 128; ++c) { base[c] = s; off[c] = s; s += cnt[c]; }
        off[128] = s;
    }
    __syncthreads();
    for (int i = 0; i < 32; ++i) {
        int j = i * 256 + tid;
        unsigned c = (is64 ? t[2 * j] : t[j]) & 127u;
        int idx = atomicAdd(&base[c], 1);
        clist[idx] = (unsigned short)j;
    }
}

// ---- per-class membership words: cm2[c*256+t] bit (q*8+e) = (tgb[q*2048+t*8+e]==c) ----
__global__ void class_masks(const unsigned char* __restrict__ tgb,
                            unsigned int* __restrict__ cm2) {
    const int c = blockIdx.x, t = threadIdx.x;
    unsigned w = 0;
#pragma unroll
    for (int q = 0; q < 4; ++q) {
        const unsigned char* base = tgb + q * 2048 + t * 8;
        unsigned b = 0;
#pragma unroll
        for (int e = 0; e < 8; ++e)
            b |= ((unsigned)(base[e] == c)) << e;
        w |= b << (8 * q);
    }
    cm2[c * 256 + t] = w;
}

// ---- L2 normalize rows, emit bf16 ----
__global__ __launch_bounds__(256) void normalize_k(const float* __restrict__ x,
                                                   unsigned short* __restrict__ nf) {
    const int wid = threadIdx.x >> 6, lane = threadIdx.x & 63;
    const size_t row = (size_t)blockIdx.x * 4 + wid;
    const float4* xr = (const float4*)(x + row * C_DIM) + lane * 2;
    float4 a = xr[0], b = xr[1];
    float ss = a.x * a.x + a.y * a.y + a.z * a.z + a.w * a.w +
               b.x * b.x + b.y * b.y + b.z * b.z + b.w * b.w;
#pragma unroll
    for (int m = 1; m < 64; m <<= 1) ss += __shfl_xor(ss, m);
    float sc = 1.0f / fmaxf(sqrtf(ss), 1e-12f);
    union { unsigned short s[8]; int4 v; } o;
    o.s[0] = f2bf(a.x * sc); o.s[1] = f2bf(a.y * sc);
    o.s[2] = f2bf(a.z * sc); o.s[3] = f2bf(a.w * sc);
    o.s[4] = f2bf(b.x * sc); o.s[5] = f2bf(b.y * sc);
    o.s[6] = f2bf(b.z * sc); o.s[7] = f2bf(b.w * sc);
    *(int4*)(nf + row * C_DIM + lane * 8) = o.v;
}

// ---- sim keys = negkey(bf16(nf @ nf^T)), 128x128 tiles (frozen R11/R12 structure) ----
__global__ __launch_bounds__(256) void gemm_sim(const unsigned short* __restrict__ nf,
                                                unsigned short* __restrict__ simk,
                                                int rowBase, int symmetric) {
    __shared__ unsigned short smem[128 * 136];
    unsigned short* As = smem;
    unsigned short* Bs = smem + 8192;
    int tI, tJ;
    if (symmetric) {
        const int idp = (NTRI - 1) - (int)blockIdx.x;   // row-major triangle order
        int u = (int)((sqrtf(8.0f * (float)idp + 1.0f) - 1.0f) * 0.5f);
        while (u * (u + 1) / 2 > idp) --u;
        while ((u + 1) * (u + 2) / 2 <= idp) ++u;
        const int v = idp - u * (u + 1) / 2;
        tI = (NT - 1) - u;
        tJ = (NT - 1) - v;
    } else {
        tI = blockIdx.y; tJ = blockIdx.x;
    }
    const int tid = threadIdx.x;
    const int wid = tid >> 6, lane = tid & 63;
    const int wm = wid >> 1, wn = wid & 1;
    const int gr = rowBase + tI * 128;
    const int gc = tJ * 128;
    f32x4 zero = {0.f, 0.f, 0.f, 0.f};
    f32x4 acc[4][4];
#pragma unroll
    for (int m = 0; m < 4; ++m)
#pragma unroll
        for (int n = 0; n < 4; ++n) acc[m][n] = zero;

    const int lr = lane >> 3, lcb = lane & 7;

    for (int k0 = 0; k0 < C_DIM; k0 += 64) {
#pragma unroll
        for (int i = 0; i < 4; ++i) {
            const int chunk = wid * 4 + i;
            const int r = chunk * 8 + lr;
            const int sc = (lcb ^ (r & 7)) << 3;
            gl_lds16(nf + (size_t)(gr + r) * C_DIM + k0 + sc, As + chunk * 512);
            gl_lds16(nf + (size_t)(gc + r) * C_DIM + k0 + sc, Bs + chunk * 512);
        }
        __syncthreads();
#pragma unroll
        for (int kk = 0; kk < 2; ++kk) {
            const int krow = kk * 32 + (lane >> 4) * 8;
            bf16x8 a[4], b[4];
#pragma unroll
            for (int m = 0; m < 4; ++m) {
                const int R = wm * 64 + m * 16 + (lane & 15);
                a[m] = *(const bf16x8*)&As[R * 64 + (krow ^ ((R & 7) << 3))];
            }
#pragma unroll
            for (int n = 0; n < 4; ++n) {
                const int R = wn * 64 + n * 16 + (lane & 15);
                b[n] = *(const bf16x8*)&Bs[R * 64 + (krow ^ ((R & 7) << 3))];
            }
#pragma unroll
            for (int m = 0; m < 4; ++m)
#pragma unroll
                for (int n = 0; n < 4; ++n)
                    acc[m][n] = __builtin_amdgcn_mfma_f32_16x16x32_bf16(a[m], b[n], acc[m][n], 0, 0, 0);
        }
        __syncthreads();
    }

    unsigned short kk4[4][4][4];
#pragma unroll
    for (int m = 0; m < 4; ++m)
#pragma unroll
        for (int n = 0; n < 4; ++n)
#pragma unroll
            for (int j = 0; j < 4; ++j)
                kk4[m][n][j] = (unsigned short)negkey(f2bf(acc[m][n][j]));

    unsigned short* Cs = smem;
    const int fc = (lane & 15);
    const int fr = (lane >> 4) << 2;

#pragma unroll
    for (int m = 0; m < 4; ++m)
#pragma unroll
        for (int n = 0; n < 4; ++n) {
            const int c = wn * 64 + n * 16 + fc;
            const int r0 = wm * 64 + m * 16 + fr;
#pragma unroll
            for (int j = 0; j < 4; ++j)
                Cs[(r0 + j) * 136 + c] = kk4[m][n][j];
        }
    __syncthreads();
#pragma unroll
    for (int k = 0; k < 8; ++k) {
        const int lin = tid + k * 256;
        const int r = lin >> 4;
        const int c0 = (lin & 15) * 8;
        int4 v = *(const int4*)&Cs[r * 136 + c0];
        *(int4*)&simk[(size_t)(gr - rowBase + r) * B_N + gc + c0] = v;
    }

    if (symmetric && tJ > tI) {
        __syncthreads();
#pragma unroll
        for (int m = 0; m < 4; ++m)
#pragma unroll
            for (int n = 0; n < 4; ++n) {
                const int c = wn * 64 + n * 16 + fc;
                const int r0 = wm * 64 + m * 16 + fr;
                ushort4 pk;
                pk.x = kk4[m][n][0]; pk.y = kk4[m][n][1];
                pk.z = kk4[m][n][2]; pk.w = kk4[m][n][3];
                *(ushort4*)&Cs[c * 136 + r0] = pk;
            }
        __syncthreads();
#pragma unroll
        for (int k = 0; k < 8; ++k) {
            const int lin = tid + k * 256;
            const int c = lin >> 4;
            const int r0 = (lin & 15) * 8;
            int4 v = *(const int4*)&Cs[c * 136 + r0];
            *(int4*)&simk[(size_t)(gc + c) * B_N + gr + r0] = v;
        }
    }
}

// ---- block-per-row selection + loss: candidate compaction above TGKEY, exact bisect ----
__global__ __launch_bounds__(256) void select_loss(const unsigned short* __restrict__ simk,
                                                   const unsigned char* __restrict__ tgb,
                                                   const unsigned int* __restrict__ cm2,
                                                   const unsigned short* __restrict__ clist,
                                                   const int* __restrict__ off,
                                                   float* __restrict__ out, int rowBase) {
    __shared__ int nlist[256];
    __shared__ float s_partial[4];
    __shared__ int nln, s_cnt;

    const int tid = threadIdx.x;
    const int wid = tid >> 6, lane = tid & 63;
    const int row = rowBase + blockIdx.x;
    const unsigned short* srow = simk + (size_t)blockIdx.x * B_N;
    const int ti = tgb[row];
    const int o0 = off[ti], o1 = off[ti + 1];

    // load 32 keys, mask same-class halves to 0 (key 0 < TGKEY: never a candidate)
    int4 A[4];
    const unsigned m = cm2[ti * 256 + tid];
#pragma unroll
    for (int q = 0; q < 4; ++q) {
        A[q] = *(const int4*)(srow + q * 2048 + tid * 8);
#pragma unroll
        for (int d = 0; d < 4; ++d) {
            unsigned two = (m >> (q * 8 + d * 2)) & 3u;
            unsigned kill = ((two & 1u) * 0xFFFFu) | (((two >> 1) & 1u) * 0xFFFF0000u);
            int v = (d == 0 ? A[q].x : d == 1 ? A[q].y : d == 2 ? A[q].z : A[q].w);
            v = (int)((unsigned)v & ~kill);
            if (d == 0) A[q].x = v; else if (d == 1) A[q].y = v;
            else if (d == 2) A[q].z = v; else A[q].w = v;
        }
    }
    if (tid == 0) { nln = 0; s_cnt = 0; }
    __syncthreads();                                             // B1

#define ELEM_LOOP(BODY)                                                          \
    _Pragma("unroll")                                                            \
    for (int q = 0; q < 4; ++q) {                                                \
        _Pragma("unroll")                                                        \
        for (int d = 0; d < 4; ++d) {                                            \
            unsigned w32 = (unsigned)(d == 0 ? A[q].x : d == 1 ? A[q].y          \
                                    : d == 2 ? A[q].z : A[q].w);                 \
            _Pragma("unroll")                                                    \
            for (int h2 = 0; h2 < 2; ++h2) {                                     \
                unsigned key = h2 ? (w32 >> 16) : (w32 & 0xFFFFu);               \
                BODY                                                             \
            }                                                                    \
        }                                                                        \
    }

    // single scan: compact candidates above the conservative pre-threshold
    ELEM_LOOP(
        if (key > TGKEY) { int p = atomicAdd(&nln, 1); if (p < 256) nlist[p] = (int)key; }
    )
    __syncthreads();                                             // B2
    const int NC = nln;

    unsigned thr;
    int kremf;
    float S;

    if (NC >= 64 && NC <= 256) {
        // -------- fast path: wave0 solo; waves 1-3 exit now --------
        if (wid != 0) return;
        // prefetch positive keys (latency hidden under bisect)
        unsigned pk[8];
#pragma unroll
        for (int s2 = 0; s2 < 8; ++s2) {
            int idx = o0 + lane + s2 * 64;
            pk[s2] = (idx < o1)
                ? ((((unsigned)srow[clist[idx]]) << 9) | ((unsigned)lane << 3) | (unsigned)s2)
                : 0xFFFFFFFFu;
        }
        // candidates into registers (4/lane, padded 0)
        int4 cw = *(const int4*)&nlist[lane * 4];
        unsigned cand[4] = {(unsigned)cw.x, (unsigned)cw.y, (unsigned)cw.z, (unsigned)cw.w};
#pragma unroll
        for (int j = 0; j < 4; ++j)
            if (lane * 4 + j >= NC) cand[j] = 0;
        // 16-step bisection: cur = exact 64th-largest key
        unsigned cur = 0;
#pragma unroll
        for (int bit = 15; bit >= 0; --bit) {
            unsigned trial = cur | (1u << bit);
            int c = (cand[0] >= trial) + (cand[1] >= trial) +
                    (cand[2] >= trial) + (cand[3] >= trial);
#pragma unroll
            for (int o = 1; o < 64; o <<= 1) c += __shfl_xor(c, o);
            if (c >= 64) cur = trial;
        }
        int r = (cand[0] > cur) + (cand[1] > cur) + (cand[2] > cur) + (cand[3] > cur);
#pragma unroll
        for (int o = 1; o < 64; o <<= 1) r += __shfl_xor(r, o);
        kremf = 64 - r;
        float f = 0.f;
#pragma unroll
        for (int j = 0; j < 4; ++j)
            if (cand[j] > cur) f += __expf(2.0f * bf2f(unkey(cand[j])));
#pragma unroll
        for (int o = 1; o < 64; o <<= 1) f += __shfl_xor(f, o);
        S = f;
        thr = cur;

        // tail: ties + positives tournament + loss
        S += (float)kremf * __expf(2.0f * bf2f(unkey(thr)));
        float acc = 0.f;
#pragma unroll
        for (int rd = 0; rd < 8; ++rd) {
            unsigned best = pk[0];
#pragma unroll
            for (int s2 = 1; s2 < 8; ++s2) best = best < pk[s2] ? best : pk[s2];
#pragma unroll
            for (int o = 1; o < 64; o <<= 1) {
                unsigned v = (unsigned)__shfl_xor((int)best, o);
                best = best < v ? best : v;
            }
            if (best != 0xFFFFFFFFu) {
                if (lane == (int)((best >> 3) & 63u)) pk[best & 7u] = 0xFFFFFFFFu;
                if (lane == 0) {
                    float p = bf2f(unkey(best >> 9));
                    acc += logf(__expf(2.0f * p) + S) - 2.0f * p;
                }
            }
        }
        if (lane == 0) out[row] = acc * 0.125f;
    } else {
        // -------- exact fallback (distribution-independent): block-wide bisection --------
        unsigned cur = 0;
        for (int bit = 15; bit >= 0; --bit) {
            unsigned trial = cur | (1u << bit);
            int c = 0;
            ELEM_LOOP( c += (key >= trial) ? 1 : 0; )
#pragma unroll
            for (int o = 1; o < 64; o <<= 1) c += __shfl_xor(c, o);
            if (lane == 0) atomicAdd(&s_cnt, c);
            __syncthreads();
            int tot = s_cnt;
            __syncthreads();
            if (tid == 0) s_cnt = 0;
            __syncthreads();
            if (tot >= 64) cur = trial;
        }
        // strict-above count
        {
            int c = 0;
            ELEM_LOOP( c += (key > cur) ? 1 : 0; )
#pragma unroll
            for (int o = 1; o < 64; o <<= 1) c += __shfl_xor(c, o);
            if (lane == 0) atomicAdd(&s_cnt, c);
            __syncthreads();
        }
        const int r = s_cnt;
        kremf = 64 - r;
        // exp-sum over strict-aboves
        {
            float f = 0.f;
            ELEM_LOOP( if (key > cur) f += __expf(2.0f * bf2f(unkey(key))); )
#pragma unroll
            for (int o = 1; o < 64; o <<= 1) f += __shfl_xor(f, o);
            if (lane == 0) s_partial[wid] = f;
            __syncthreads();
        }
        if (wid != 0) return;
        S = s_partial[0] + s_partial[1] + s_partial[2] + s_partial[3];
        thr = cur;

        unsigned pk[8];
#pragma unroll
        for (int s2 = 0; s2 < 8; ++s2) {
            int idx = o0 + lane + s2 * 64;
            pk[s2] = (idx < o1)
                ? ((((unsigned)srow[clist[idx]]) << 9) | ((unsigned)lane << 3) | (unsigned)s2)
                : 0xFFFFFFFFu;
        }
        S += (float)kremf * __expf(2.0f * bf2f(unkey(thr)));
        float acc = 0.f;
#pragma unroll
        for (int rd = 0; rd < 8; ++rd) {
            unsigned best = pk[0];
#pragma unroll
            for (int s2 = 1; s2 < 8; ++s2) best = best < pk[s2] ? best : pk[s2];
#pragma unroll
            for (int o = 1; o < 64; o <<= 1) {
                unsigned v = (unsigned)__shfl_xor((int)best, o);
                best = best < v ? best : v;
            }
            if (best != 0xFFFFFFFFu) {
                if (lane == (int)((best >> 3) & 63u)) pk[best & 7u] = 0xFFFFFFFFu;
                if (lane == 0) {
                    float p = bf2f(unkey(best >> 9));
                    acc += logf(__expf(2.0f * p) + S) - 2.0f * p;
                }
            }
        }
        if (lane == 0) out[row] = acc * 0.125f;
    }
#undef ELEM_LOOP
}

extern "C" void kernel_launch(void* const* d_in, const int* in_sizes, int n_in,
                              void* d_out, int out_size, void* d_ws, size_t ws_size,
                              hipStream_t stream) {
    const float* newf = (const float*)d_in[1];
    const unsigned int* tgtw = (const unsigned int*)d_in[2];
    float* out = (float*)d_out;
    char* ws = (char*)d_ws;
    unsigned char* tgb = (unsigned char*)ws;                          // 8 KB
    unsigned int* cm2 = (unsigned int*)(ws + 8192);                   // 100 KB
    int* off = (int*)(ws + 110592);                                   // 1 KB (129 ints)
    unsigned short* clist = (unsigned short*)(ws + 111616);           // 16 KB
    unsigned short* nf = (unsigned short*)(ws + 131072);              // 8 MB (4K-aligned)
    unsigned short* simk = (unsigned short*)(ws + 131072 + (size_t)B_N * C_DIM * 2);

    size_t fixed = 131072 + (size_t)B_N * C_DIM * 2;
    size_t avail = (ws_size > fixed) ? (ws_size - fixed) : 0;
    long maxRows = (long)(avail / ((size_t)B_N * 2));
    int chunk = (int)((maxRows / 128) * 128);
    if (chunk < 128) chunk = 128;
    if (chunk > B_N) chunk = B_N;

    hipLaunchKernelGGL(prep_all, dim3(1), dim3(256), 0, stream, tgtw, tgb, clist, off);
    hipLaunchKernelGGL(class_masks, dim3(100), dim3(256), 0, stream, tgb, cm2);
    hipLaunchKernelGGL(normalize_k, dim3(B_N / 4), dim3(256), 0, stream, newf, nf);
    if (chunk == B_N) {
        hipLaunchKernelGGL(gemm_sim, dim3(NTRI), dim3(256), 0, stream, nf, simk, 0, 1);
        hipLaunchKernelGGL(select_loss, dim3(B_N), dim3(256), 0, stream,
                           simk, tgb, cm2, clist, off, out, 0);
    } else {
        for (int r0 = 0; r0 < B_N; r0 += chunk) {
            int rows = (B_N - r0 < chunk) ? (B_N - r0) : chunk;
            hipLaunchKernelGGL(gemm_sim, dim3(64, rows / 128), dim3(256), 0, stream,
                               nf, simk, r0, 0);
            hipLaunchKernelGGL(select_loss, dim3(rows), dim3(256), 0, stream,
                               simk, tgb, cm2, clist, off, out, r0);
        }
    }
}